// Round 8
// baseline (12030.853 us; speedup 1.0000x reference)
//
#include <hip/hip_runtime.h>

// SpikeMLP — R19: W-only LDS + wave-uniform f32 A (scalar/broadcast loads).
// Chain contract (FROZEN, verified absmax=0.0 @ R14-R16,R18): per C element
//   acc = fma(a_k, w_k, acc), k = 0..1023 strictly ascending, single
//   accumulator, fp32, contract off. Spikes exactly 0/1 in f32 ->
//   format-free products. Recurrence fp32 ufunc order.
// Bottleneck model (explains R14-R18): per-CU DS pipe ~12cyc/wave-b128
//   (m134). R14: 2.25x over DS budget (44% cap). R15/16: 1.5x (~60%).
//   R17: bf16 unpack on VALU. R18: VGPR starvation (76 vs ~130 needed).
// R19: lane tile 16m x 4n, wave owns 16 rows (A wave-uniform -> scalar
//   s_load, f32, no unpack), W k-major LDS from pre-transposed Wt:
//   DS/kk = 12 read + 3 staging per 128 VALU-cyc -> x4 waves = 0.47 util.
//   __launch_bounds__(256,3) -> VGPR cap 168 (acc 64 + stage 32 + ops).
//   R14's proven 2-barrier cadence; Wt scratch in d_out (R18, passed).
// Predicted: VALUBusy >=85% FMA-dominant, big GEMM ~1000-1150us,
//   total ~2.9-3.1ms, absmax 0.0.

typedef float floatx4 __attribute__((ext_vector_type(4)));

static constexpr int BSZ   = 4096;
static constexpr int D_IN  = 1024;
static constexpr int H1    = 1024;
static constexpr int D_OUT = 512;
static constexpr int M_ROWS = BSZ * 16;   // 65536, m = b*16 + t

// ---------------------------------------------------------------------------
// pack X [B, D_in, T=16] f32 -> A [m = b*16 + t][d] f32 (spikes exactly 0/1)
// ---------------------------------------------------------------------------
__global__ void pack_x(const float* __restrict__ X, float* __restrict__ A) {
    const int P = blockIdx.x * 256 + threadIdx.x;     // P = b*1024 + d
    const int b = P >> 10, d = P & 1023;
    const float4* xp = (const float4*)(X + (size_t)P * 16);
    float4 x0 = xp[0], x1 = xp[1], x2 = xp[2], x3 = xp[3];
    const float v[16] = {x0.x, x0.y, x0.z, x0.w, x1.x, x1.y, x1.z, x1.w,
                         x2.x, x2.y, x2.z, x2.w, x3.x, x3.y, x3.z, x3.w};
#pragma unroll
    for (int t = 0; t < 16; ++t)
        A[((size_t)(b * 16 + t)) * 1024 + d] = v[t];
}

// ---------------------------------------------------------------------------
// W [R][1024] -> Wt [1024][R]  (pure copy, bit-exact)
// ---------------------------------------------------------------------------
__global__ void transp(const float* __restrict__ W, float* __restrict__ Wt,
                       int R) {
    const int P = blockIdx.x * 256 + threadIdx.x;   // n*1024 + k
    const int k = P & 1023, n = P >> 10;
    Wt[(size_t)k * R + n] = W[P];
}

// ---------------------------------------------------------------------------
// GEMM, reference fp32 chain. C[m][n] = A[m,:] . W[n,:], K = 1024.
// Block: 64 m (4 waves x 16 rows) x 256 n. Lane tile 16m x 4n (64 acc).
// A: wave-uniform scalar loads (f32). W: k-major LDS, BK=32, staged from
// Wt with coalesced float4 reads + conflict-free ds_write_b128.
// Single ascending accumulator over full K (frozen chain).
// ---------------------------------------------------------------------------
__global__ __launch_bounds__(256, 3) void gemm_np(
    const float* __restrict__ A,    // [M, 1024] f32 spikes (exactly 0/1)
    const float* __restrict__ Wt,   // [1024, N] f32 (k-major transpose of W)
    float* __restrict__ C,          // [M, N] fp32
    int N) {
#pragma clang fp contract(off)
    __shared__ float Ws[32][256];   // [kk][n]  32 KB

    const int tid  = threadIdx.x;
    const int lane = tid & 63;
    const int wv   = __builtin_amdgcn_readfirstlane(tid >> 6);  // wave 0..3
    const int m0   = blockIdx.x * 64 + wv * 16;    // wave's 16 m-rows
    const int n0   = blockIdx.y * 256;             // block n range

    // A: wave-uniform row base (f32, row stride 1024)
    const float* Ar = A + (size_t)m0 * 1024;

    // W staging: wave wv stages LDS rows wv*8 .. wv*8+7; lane covers 4 n
    const float* Wstage = Wt + (size_t)(wv * 8) * N + n0 + lane * 4;
    const int swrow = wv * 8, scol = lane * 4;

    float acc[16][4] = {};   // single-chain accumulators

    for (int kt = 0; kt < 32; ++kt) {
        const int k0 = kt * 32;
        // W-tile global reads (issue before barrier; hide under prev compute)
        float4 wst[8];
#pragma unroll
        for (int e = 0; e < 8; ++e)
            wst[e] = *(const float4*)(Wstage + (size_t)(k0 + e) * N);
        __syncthreads();             // previous tile fully consumed
#pragma unroll
        for (int e = 0; e < 8; ++e)
            *(float4*)&Ws[swrow + e][scol] = wst[e];
        __syncthreads();

        // compute: k strictly ascending; a wave-uniform (scalar), w from LDS
#pragma unroll
        for (int g = 0; g < 8; ++g) {
            floatx4 av[16];          // 16 rows x 4 k (uniform -> SGPR)
#pragma unroll
            for (int i = 0; i < 16; ++i)
                av[i] = *(const floatx4*)(Ar + (size_t)i * 1024 + k0 + g * 4);
#pragma unroll
            for (int k2 = 0; k2 < 4; ++k2) {
                const floatx4 wv4 = *(const floatx4*)&Ws[g * 4 + k2][lane * 4];
#pragma unroll
                for (int i = 0; i < 16; ++i) {
                    const float ai = av[i][k2];
                    acc[i][0] = __builtin_fmaf(ai, wv4[0], acc[i][0]);
                    acc[i][1] = __builtin_fmaf(ai, wv4[1], acc[i][1]);
                    acc[i][2] = __builtin_fmaf(ai, wv4[2], acc[i][2]);
                    acc[i][3] = __builtin_fmaf(ai, wv4[3], acc[i][3]);
                }
            }
        }
    }

#pragma unroll
    for (int i = 0; i < 16; ++i) {
        floatx4 st = {acc[i][0], acc[i][1], acc[i][2], acc[i][3]};
        *(floatx4*)&C[(size_t)(m0 + i) * N + n0 + lane * 4] = st;
    }
}

// ---------------------------------------------------------------------------
// fp32 LIF recurrence, numpy ufunc order, contraction off (frozen).
// In-place: Z holds GEMM output, overwritten with f32 spikes (exact 0/1).
// ---------------------------------------------------------------------------
__global__ void recur_hidden(float* __restrict__ Z, const float* __restrict__ bias) {
#pragma clang fp contract(off)
    const int idx = blockIdx.x * 256 + threadIdx.x;   // b*1024 + n
    const int n = idx & 1023, b = idx >> 10;
    const float bb = bias[n];
    float c = 0.f, v = 0.f, s = 0.f;
#pragma unroll
    for (int t = 0; t < 16; ++t) {
        const size_t p = (size_t)(b * 16 + t) * 1024 + n;
        const float z = Z[p];
        const float t1 = c * 0.5f;
        const float t2 = t1 + z;
        c = t2 + bb;
        const float u1 = v * 0.75f;
        const float u2 = u1 * (1.0f - s);
        v = u2 + c;
        s = (v > 0.5f) ? 1.0f : 0.0f;
        Z[p] = s;                                     // exact 0/1 f32
    }
}

__global__ void recur_out(const float* __restrict__ Z, const float* __restrict__ bias,
                          float* __restrict__ Out) {
#pragma clang fp contract(off)
    const int idx = blockIdx.x * 256 + threadIdx.x;   // b*512 + n
    const int n = idx & 511, b = idx >> 9;
    const float bb = bias[n];
    float c = 0.f, v = 0.f, s = 0.f, acm = 0.f;
#pragma unroll
    for (int t = 0; t < 16; ++t) {
        const float z = Z[(size_t)(b * 16 + t) * 512 + n];
        const float t1 = c * 0.5f;
        const float t2 = t1 + z;
        c = t2 + bb;
        const float u1 = v * 0.75f;
        const float u2 = u1 * (1.0f - s);
        v = u2 + c;
        s = (v > 0.5f) ? 1.0f : 0.0f;
        acm += s;                                     // small ints, exact
    }
    Out[(size_t)b * 512 + n] = acm * 0.0625f;         // exact (2^-4)
}

// ---------------------------------------------------------------------------
extern "C" void kernel_launch(void* const* d_in, const int* in_sizes, int n_in,
                              void* d_out, int out_size, void* d_ws, size_t ws_size,
                              hipStream_t stream) {
    const float* X  = (const float*)d_in[0];
    const float* W1 = (const float*)d_in[1];
    const float* b1 = (const float*)d_in[2];
    const float* W2 = (const float*)d_in[3];
    const float* b2 = (const float*)d_in[4];
    const float* Wo = (const float*)d_in[5];
    const float* bo = (const float*)d_in[6];

    char* ws = (char*)d_ws;
    float* buf0 = (float*)ws;                      // 256 MiB (A1 / S2)
    float* buf1 = (float*)(ws + (256ull << 20));   // 256 MiB (Z1=S1 / Z3)
    float* WT   = (float*)d_out;                   // 4 MiB scratch in d_out
                                                   // (8 MiB; fully rewritten
                                                   //  by recur_out at the end)

    pack_x<<<(BSZ * D_IN) / 256, 256, 0, stream>>>(X, buf0);

    // layer 1: A=buf0 -> Z=buf1, spikes in-place in buf1
    transp<<<(H1 * 1024) / 256, 256, 0, stream>>>(W1, WT, H1);
    gemm_np<<<dim3(M_ROWS / 64, H1 / 256), 256, 0, stream>>>(buf0, WT, buf1, H1);
    recur_hidden<<<(BSZ * H1) / 256, 256, 0, stream>>>(buf1, b1);
    // layer 2: A=buf1 -> Z=buf0, spikes in-place in buf0
    transp<<<(H1 * 1024) / 256, 256, 0, stream>>>(W2, WT, H1);
    gemm_np<<<dim3(M_ROWS / 64, H1 / 256), 256, 0, stream>>>(buf1, WT, buf0, H1);
    recur_hidden<<<(BSZ * H1) / 256, 256, 0, stream>>>(buf0, b2);
    // output layer: A=buf0 -> Z=buf1 [M,512]
    transp<<<(D_OUT * 1024) / 256, 256, 0, stream>>>(Wo, WT, D_OUT);
    gemm_np<<<dim3(M_ROWS / 64, D_OUT / 256), 256, 0, stream>>>(buf0, WT, buf1, D_OUT);
    recur_out<<<(BSZ * D_OUT) / 256, 256, 0, stream>>>(buf1, bo, (float*)d_out);
}

// Round 9
// 3889.613 us; speedup vs baseline: 3.0931x; 3.0931x over previous
//
#include <hip/hip_runtime.h>

// SpikeMLP — R20: R15 structure (measured best, 3842us) + proven VGPR fix.
// Chain contract (FROZEN, verified absmax=0.0 @ R14/R15/R16/R18/R19):
//   per C element: acc = fma(a_k, w_k, acc), k = 0..1023 strictly
//   ascending, single accumulator, fp32, contract off. Spikes exactly
//   0/1 (format-free). Recurrence fp32 ufunc order. MFMA forbidden.
// Evidence ledger:
//   R15 (128x128, 8x8, 1-buf): 1713us/GEMM, VGPR=68 -> AGPR shuffle ~35%
//   R16 (+dbuf +LB(256,2)):    1810us, VGPR=128 (fix worked; dbuf hurt)
//   R18 (LDS-free):            3348us, VGPR=76  (starved pipeline)
//   R19 (SGPR-A attempt):      4696us, WRITE 4.3GB = scratch spills
// R20 = R15 + __launch_bounds__(256,2) [the ONLY proven 128-VGPR lever]
//   + f32 activations (no cvt in staging; in-place recurrence from R18).
//   Single 32KB LDS buffer, 2 barriers/ktile, 4 blocks/CU.
// Predicted: VGPR ~128, WRITE_SIZE 262MB (no scratch), VALUBusy ~85%
//   FMA-dominant, big GEMM ~1400-1500us, total ~3.2-3.4ms, absmax 0.0.

static constexpr int BSZ   = 4096;
static constexpr int D_IN  = 1024;
static constexpr int H1    = 1024;
static constexpr int D_OUT = 512;
static constexpr int M_ROWS = BSZ * 16;   // 65536, m = b*16 + t

// ---------------------------------------------------------------------------
// pack X [B, D_in, T=16] f32 -> A [m = b*16 + t][d] f32 (spikes exactly 0/1)
// ---------------------------------------------------------------------------
__global__ void pack_x(const float* __restrict__ X, float* __restrict__ A) {
    const int P = blockIdx.x * 256 + threadIdx.x;     // P = b*1024 + d
    const int b = P >> 10, d = P & 1023;
    const float4* xp = (const float4*)(X + (size_t)P * 16);
    float4 x0 = xp[0], x1 = xp[1], x2 = xp[2], x3 = xp[3];
    const float v[16] = {x0.x, x0.y, x0.z, x0.w, x1.x, x1.y, x1.z, x1.w,
                         x2.x, x2.y, x2.z, x2.w, x3.x, x3.y, x3.z, x3.w};
#pragma unroll
    for (int t = 0; t < 16; ++t)
        A[((size_t)(b * 16 + t)) * 1024 + d] = v[t];
}

// ---------------------------------------------------------------------------
// GEMM, reference fp32 chain. C[m][n] = A[m,:] . W[n,:], K = 1024.
// Block 128(M) x 128(N), 256 threads, 8x8 per thread. BK = 32, k-major LDS,
// single buffer, 2 barriers/ktile (R15 structure — measured best).
// Thread (tx,ty): rows ty*8..+7, cols {tx*4..+3, 64+tx*4..+3}.
// ---------------------------------------------------------------------------
__global__ __launch_bounds__(256, 2) void gemm_np(
    const float* __restrict__ A,    // [M, 1024] f32 spikes (exactly 0/1)
    const float* __restrict__ W,    // [N, 1024] f32 weights (raw input)
    float* __restrict__ C,          // [M, N] fp32
    int N) {
#pragma clang fp contract(off)
    __shared__ float As[32][128];   // [kk][m]  16 KB
    __shared__ float Ws[32][128];   // [kk][n]  16 KB

    const int tid = threadIdx.x;
    const int tx = tid & 15;        // n quads: tx*4 and 64+tx*4
    const int ty = tid >> 4;        // m group: rows ty*8 .. ty*8+7
    const int m0 = blockIdx.x * 128, n0 = blockIdx.y * 128;

    const int arow = tid & 127, akh = tid >> 7;   // staging: row, k-half

    const float* Ab = A + (size_t)(m0 + arow) * 1024 + akh * 16;
    const float* Wb = W + (size_t)(n0 + arow) * 1024 + akh * 16;

    float pacc[8][8] = {};   // single-chain accumulators

    for (int kt = 0; kt < 32; ++kt) {
        const int k0 = kt * 32;
        // global reads (issue before barrier)
        float4 av0 = *(const float4*)(Ab + k0);
        float4 av1 = *(const float4*)(Ab + k0 + 4);
        float4 av2 = *(const float4*)(Ab + k0 + 8);
        float4 av3 = *(const float4*)(Ab + k0 + 12);
        float4 wv0 = *(const float4*)(Wb + k0);
        float4 wv1 = *(const float4*)(Wb + k0 + 4);
        float4 wv2 = *(const float4*)(Wb + k0 + 8);
        float4 wv3 = *(const float4*)(Wb + k0 + 12);
        __syncthreads();             // previous tile fully consumed
        {
            const float avv[16] = {av0.x, av0.y, av0.z, av0.w,
                                   av1.x, av1.y, av1.z, av1.w,
                                   av2.x, av2.y, av2.z, av2.w,
                                   av3.x, av3.y, av3.z, av3.w};
            const float wvv[16] = {wv0.x, wv0.y, wv0.z, wv0.w,
                                   wv1.x, wv1.y, wv1.z, wv1.w,
                                   wv2.x, wv2.y, wv2.z, wv2.w,
                                   wv3.x, wv3.y, wv3.z, wv3.w};
#pragma unroll
            for (int c = 0; c < 16; ++c) {
                As[akh * 16 + c][arow] = avv[c];   // coalesced b32, 2-way ok
                Ws[akh * 16 + c][arow] = wvv[c];
            }
        }
        __syncthreads();

#pragma unroll
        for (int kk = 0; kk < 32; ++kk) {         // strictly k-ascending
            float4 a0 = *(const float4*)&As[kk][ty * 8];
            float4 a1 = *(const float4*)&As[kk][ty * 8 + 4];
            float4 w0 = *(const float4*)&Ws[kk][tx * 4];
            float4 w1 = *(const float4*)&Ws[kk][64 + tx * 4];
            const float a[8] = {a0.x, a0.y, a0.z, a0.w, a1.x, a1.y, a1.z, a1.w};
            const float w[8] = {w0.x, w0.y, w0.z, w0.w, w1.x, w1.y, w1.z, w1.w};
#pragma unroll
            for (int i = 0; i < 8; ++i)
#pragma unroll
                for (int j = 0; j < 8; ++j)
                    pacc[i][j] = __builtin_fmaf(a[i], w[j], pacc[i][j]);
        }
    }

#pragma unroll
    for (int i = 0; i < 8; ++i) {
        float4 s0 = {pacc[i][0], pacc[i][1], pacc[i][2], pacc[i][3]};
        float4 s1 = {pacc[i][4], pacc[i][5], pacc[i][6], pacc[i][7]};
        const size_t r = (size_t)(m0 + ty * 8 + i) * N;
        *(float4*)&C[r + n0 + tx * 4]      = s0;
        *(float4*)&C[r + n0 + 64 + tx * 4] = s1;
    }
}

// ---------------------------------------------------------------------------
// fp32 LIF recurrence, numpy ufunc order, contraction off (frozen).
// In-place: Z holds GEMM output, overwritten with f32 spikes (exact 0/1).
// ---------------------------------------------------------------------------
__global__ void recur_hidden(float* __restrict__ Z, const float* __restrict__ bias) {
#pragma clang fp contract(off)
    const int idx = blockIdx.x * 256 + threadIdx.x;   // b*1024 + n
    const int n = idx & 1023, b = idx >> 10;
    const float bb = bias[n];
    float c = 0.f, v = 0.f, s = 0.f;
#pragma unroll
    for (int t = 0; t < 16; ++t) {
        const size_t p = (size_t)(b * 16 + t) * 1024 + n;
        const float z = Z[p];
        const float t1 = c * 0.5f;
        const float t2 = t1 + z;
        c = t2 + bb;
        const float u1 = v * 0.75f;
        const float u2 = u1 * (1.0f - s);
        v = u2 + c;
        s = (v > 0.5f) ? 1.0f : 0.0f;
        Z[p] = s;                                     // exact 0/1 f32
    }
}

__global__ void recur_out(const float* __restrict__ Z, const float* __restrict__ bias,
                          float* __restrict__ Out) {
#pragma clang fp contract(off)
    const int idx = blockIdx.x * 256 + threadIdx.x;   // b*512 + n
    const int n = idx & 511, b = idx >> 9;
    const float bb = bias[n];
    float c = 0.f, v = 0.f, s = 0.f, acm = 0.f;
#pragma unroll
    for (int t = 0; t < 16; ++t) {
        const float z = Z[(size_t)(b * 16 + t) * 512 + n];
        const float t1 = c * 0.5f;
        const float t2 = t1 + z;
        c = t2 + bb;
        const float u1 = v * 0.75f;
        const float u2 = u1 * (1.0f - s);
        v = u2 + c;
        s = (v > 0.5f) ? 1.0f : 0.0f;
        acm += s;                                     // small ints, exact
    }
    Out[(size_t)b * 512 + n] = acm * 0.0625f;         // exact (2^-4)
}

// ---------------------------------------------------------------------------
extern "C" void kernel_launch(void* const* d_in, const int* in_sizes, int n_in,
                              void* d_out, int out_size, void* d_ws, size_t ws_size,
                              hipStream_t stream) {
    const float* X  = (const float*)d_in[0];
    const float* W1 = (const float*)d_in[1];
    const float* b1 = (const float*)d_in[2];
    const float* W2 = (const float*)d_in[3];
    const float* b2 = (const float*)d_in[4];
    const float* Wo = (const float*)d_in[5];
    const float* bo = (const float*)d_in[6];

    char* ws = (char*)d_ws;
    float* buf0 = (float*)ws;                      // 256 MiB (A1 / Z2=S2)
    float* buf1 = (float*)(ws + (256ull << 20));   // 256 MiB (Z1=S1 / Z3)

    pack_x<<<(BSZ * D_IN) / 256, 256, 0, stream>>>(X, buf0);

    // layer 1: A=buf0 -> Z=buf1, spikes in-place in buf1
    gemm_np<<<dim3(M_ROWS / 128, H1 / 128), 256, 0, stream>>>(buf0, W1, buf1, H1);
    recur_hidden<<<(BSZ * H1) / 256, 256, 0, stream>>>(buf1, b1);
    // layer 2: A=buf1 -> Z=buf0 (overwrites A1, no longer needed)
    gemm_np<<<dim3(M_ROWS / 128, H1 / 128), 256, 0, stream>>>(buf1, W2, buf0, H1);
    recur_hidden<<<(BSZ * H1) / 256, 256, 0, stream>>>(buf0, b2);
    // output layer: A=buf0 -> Z=buf1 [M,512]
    gemm_np<<<dim3(M_ROWS / 128, D_OUT / 128), 256, 0, stream>>>(buf0, Wo, buf1, D_OUT);
    recur_out<<<(BSZ * D_OUT) / 256, 256, 0, stream>>>(buf1, bo, (float*)d_out);
}

// Round 10
// 3816.133 us; speedup vs baseline: 3.1526x; 1.0193x over previous
//
#include <hip/hip_runtime.h>

// SpikeMLP — R21: packed-FP32 FMA (v_pk_fma_f32) on the R20 structure.
// Chain contract (FROZEN, verified absmax=0.0 @ R14-R16,R18-R20):
//   per C element: acc = fma(a_k, w_k, acc), k = 0..1023 strictly
//   ascending, single accumulator, fp32, contract off. v_pk_fma_f32 =
//   two INDEPENDENT IEEE fp32 fmas; pairing is across adjacent n-columns
//   (j), NEVER across k -> per-element chain bit-identical.
// Evidence ledger:
//   R14 8x4 (1.5 B/FMA): 1758us | R15/R20 8x8 (1.0 B/FMA): 1713us
//   -> equal times despite 1.5x LDS-byte difference => NOT purely
//   LDS-bytes-bound; shared issue budget (64 FMA + 4 DS + staging) is
//   the lead theory. R21 halves FMA issue slots at identical FLOPs.
// Implementation: __builtin_elementwise_fma on float2 (backend forms
//   v_pk_fma_f32 via packed-fp32; worst case scalarizes = status quo).
// Pre-committed read: GEMM ~1150-1350us => issue-bound confirmed;
//   flat (<5%) => LDS-bound, next round cuts LDS traffic.
// Predicted: VGPR ~72-96, LDS 32768, WRITE 262MB, absmax 0.0,
//   total ~2.9-3.2ms (if issue-bound).

typedef float f2 __attribute__((ext_vector_type(2)));

static constexpr int BSZ   = 4096;
static constexpr int D_IN  = 1024;
static constexpr int H1    = 1024;
static constexpr int D_OUT = 512;
static constexpr int M_ROWS = BSZ * 16;   // 65536, m = b*16 + t

// ---------------------------------------------------------------------------
// pack X [B, D_in, T=16] f32 -> A [m = b*16 + t][d] f32 (spikes exactly 0/1)
// ---------------------------------------------------------------------------
__global__ void pack_x(const float* __restrict__ X, float* __restrict__ A) {
    const int P = blockIdx.x * 256 + threadIdx.x;     // P = b*1024 + d
    const int b = P >> 10, d = P & 1023;
    const float4* xp = (const float4*)(X + (size_t)P * 16);
    float4 x0 = xp[0], x1 = xp[1], x2 = xp[2], x3 = xp[3];
    const float v[16] = {x0.x, x0.y, x0.z, x0.w, x1.x, x1.y, x1.z, x1.w,
                         x2.x, x2.y, x2.z, x2.w, x3.x, x3.y, x3.z, x3.w};
#pragma unroll
    for (int t = 0; t < 16; ++t)
        A[((size_t)(b * 16 + t)) * 1024 + d] = v[t];
}

// ---------------------------------------------------------------------------
// GEMM, reference fp32 chain. C[m][n] = A[m,:] . W[n,:], K = 1024.
// Block 128(M) x 128(N), 256 threads, 8x8 per thread. BK = 32, k-major LDS,
// single buffer, 2 barriers/ktile (R15/R20 structure — measured best).
// Inner FMAs as float2 packed pairs over adjacent n-columns.
// ---------------------------------------------------------------------------
__global__ __launch_bounds__(256, 2) void gemm_np(
    const float* __restrict__ A,    // [M, 1024] f32 spikes (exactly 0/1)
    const float* __restrict__ W,    // [N, 1024] f32 weights (raw input)
    float* __restrict__ C,          // [M, N] fp32
    int N) {
#pragma clang fp contract(off)
    __shared__ float As[32][128];   // [kk][m]  16 KB
    __shared__ float Ws[32][128];   // [kk][n]  16 KB

    const int tid = threadIdx.x;
    const int tx = tid & 15;        // n quads: tx*4 and 64+tx*4
    const int ty = tid >> 4;        // m group: rows ty*8 .. ty*8+7
    const int m0 = blockIdx.x * 128, n0 = blockIdx.y * 128;

    const int arow = tid & 127, akh = tid >> 7;   // staging: row, k-half

    const float* Ab = A + (size_t)(m0 + arow) * 1024 + akh * 16;
    const float* Wb = W + (size_t)(n0 + arow) * 1024 + akh * 16;

    f2 acc2[8][4] = {};   // single-chain accumulators, paired over n

    for (int kt = 0; kt < 32; ++kt) {
        const int k0 = kt * 32;
        // global reads (issue before barrier)
        float4 av0 = *(const float4*)(Ab + k0);
        float4 av1 = *(const float4*)(Ab + k0 + 4);
        float4 av2 = *(const float4*)(Ab + k0 + 8);
        float4 av3 = *(const float4*)(Ab + k0 + 12);
        float4 wv0 = *(const float4*)(Wb + k0);
        float4 wv1 = *(const float4*)(Wb + k0 + 4);
        float4 wv2 = *(const float4*)(Wb + k0 + 8);
        float4 wv3 = *(const float4*)(Wb + k0 + 12);
        __syncthreads();             // previous tile fully consumed
        {
            const float avv[16] = {av0.x, av0.y, av0.z, av0.w,
                                   av1.x, av1.y, av1.z, av1.w,
                                   av2.x, av2.y, av2.z, av2.w,
                                   av3.x, av3.y, av3.z, av3.w};
            const float wvv[16] = {wv0.x, wv0.y, wv0.z, wv0.w,
                                   wv1.x, wv1.y, wv1.z, wv1.w,
                                   wv2.x, wv2.y, wv2.z, wv2.w,
                                   wv3.x, wv3.y, wv3.z, wv3.w};
#pragma unroll
            for (int c = 0; c < 16; ++c) {
                As[akh * 16 + c][arow] = avv[c];   // coalesced b32, 2-way ok
                Ws[akh * 16 + c][arow] = wvv[c];
            }
        }
        __syncthreads();

#pragma unroll
        for (int kk = 0; kk < 32; ++kk) {         // strictly k-ascending
            float4 a0 = *(const float4*)&As[kk][ty * 8];
            float4 a1 = *(const float4*)&As[kk][ty * 8 + 4];
            float4 w0 = *(const float4*)&Ws[kk][tx * 4];
            float4 w1 = *(const float4*)&Ws[kk][64 + tx * 4];
            const float a[8] = {a0.x, a0.y, a0.z, a0.w, a1.x, a1.y, a1.z, a1.w};
            const f2 w2[4] = {{w0.x, w0.y}, {w0.z, w0.w},
                              {w1.x, w1.y}, {w1.z, w1.w}};
#pragma unroll
            for (int i = 0; i < 8; ++i) {
                const f2 ai = {a[i], a[i]};
#pragma unroll
                for (int jp = 0; jp < 4; ++jp)
                    acc2[i][jp] = __builtin_elementwise_fma(ai, w2[jp], acc2[i][jp]);
            }
        }
    }

#pragma unroll
    for (int i = 0; i < 8; ++i) {
        float4 s0 = {acc2[i][0][0], acc2[i][0][1], acc2[i][1][0], acc2[i][1][1]};
        float4 s1 = {acc2[i][2][0], acc2[i][2][1], acc2[i][3][0], acc2[i][3][1]};
        const size_t r = (size_t)(m0 + ty * 8 + i) * N;
        *(float4*)&C[r + n0 + tx * 4]      = s0;
        *(float4*)&C[r + n0 + 64 + tx * 4] = s1;
    }
}

// ---------------------------------------------------------------------------
// fp32 LIF recurrence, numpy ufunc order, contraction off (frozen).
// In-place: Z holds GEMM output, overwritten with f32 spikes (exact 0/1).
// ---------------------------------------------------------------------------
__global__ void recur_hidden(float* __restrict__ Z, const float* __restrict__ bias) {
#pragma clang fp contract(off)
    const int idx = blockIdx.x * 256 + threadIdx.x;   // b*1024 + n
    const int n = idx & 1023, b = idx >> 10;
    const float bb = bias[n];
    float c = 0.f, v = 0.f, s = 0.f;
#pragma unroll
    for (int t = 0; t < 16; ++t) {
        const size_t p = (size_t)(b * 16 + t) * 1024 + n;
        const float z = Z[p];
        const float t1 = c * 0.5f;
        const float t2 = t1 + z;
        c = t2 + bb;
        const float u1 = v * 0.75f;
        const float u2 = u1 * (1.0f - s);
        v = u2 + c;
        s = (v > 0.5f) ? 1.0f : 0.0f;
        Z[p] = s;                                     // exact 0/1 f32
    }
}

__global__ void recur_out(const float* __restrict__ Z, const float* __restrict__ bias,
                          float* __restrict__ Out) {
#pragma clang fp contract(off)
    const int idx = blockIdx.x * 256 + threadIdx.x;   // b*512 + n
    const int n = idx & 511, b = idx >> 9;
    const float bb = bias[n];
    float c = 0.f, v = 0.f, s = 0.f, acm = 0.f;
#pragma unroll
    for (int t = 0; t < 16; ++t) {
        const float z = Z[(size_t)(b * 16 + t) * 512 + n];
        const float t1 = c * 0.5f;
        const float t2 = t1 + z;
        c = t2 + bb;
        const float u1 = v * 0.75f;
        const float u2 = u1 * (1.0f - s);
        v = u2 + c;
        s = (v > 0.5f) ? 1.0f : 0.0f;
        acm += s;                                     // small ints, exact
    }
    Out[(size_t)b * 512 + n] = acm * 0.0625f;         // exact (2^-4)
}

// ---------------------------------------------------------------------------
extern "C" void kernel_launch(void* const* d_in, const int* in_sizes, int n_in,
                              void* d_out, int out_size, void* d_ws, size_t ws_size,
                              hipStream_t stream) {
    const float* X  = (const float*)d_in[0];
    const float* W1 = (const float*)d_in[1];
    const float* b1 = (const float*)d_in[2];
    const float* W2 = (const float*)d_in[3];
    const float* b2 = (const float*)d_in[4];
    const float* Wo = (const float*)d_in[5];
    const float* bo = (const float*)d_in[6];

    char* ws = (char*)d_ws;
    float* buf0 = (float*)ws;                      // 256 MiB (A1 / Z2=S2)
    float* buf1 = (float*)(ws + (256ull << 20));   // 256 MiB (Z1=S1 / Z3)

    pack_x<<<(BSZ * D_IN) / 256, 256, 0, stream>>>(X, buf0);

    // layer 1: A=buf0 -> Z=buf1, spikes in-place in buf1
    gemm_np<<<dim3(M_ROWS / 128, H1 / 128), 256, 0, stream>>>(buf0, W1, buf1, H1);
    recur_hidden<<<(BSZ * H1) / 256, 256, 0, stream>>>(buf1, b1);
    // layer 2: A=buf1 -> Z=buf0 (overwrites A1, no longer needed)
    gemm_np<<<dim3(M_ROWS / 128, H1 / 128), 256, 0, stream>>>(buf1, W2, buf0, H1);
    recur_hidden<<<(BSZ * H1) / 256, 256, 0, stream>>>(buf0, b2);
    // output layer: A=buf0 -> Z=buf1 [M,512]
    gemm_np<<<dim3(M_ROWS / 128, D_OUT / 128), 256, 0, stream>>>(buf0, Wo, buf1, D_OUT);
    recur_out<<<(BSZ * D_OUT) / 256, 256, 0, stream>>>(buf1, bo, (float*)d_out);
}